// Round 14
// baseline (68.001 us; speedup 1.0000x reference)
//
#include <hip/hip_runtime.h>
#include <stdint.h>

#define N_NODES 100000
#define N_EDGES 1600000
#define IN_F 128
#define OUT_F 32

#define RB 64                     // rows per bucket (shift 6)
#define NB 1563                   // ceil(N_NODES / RB)
#define BBLK 320                  // bin blocks
#define EPA (N_EDGES / BBLK)      // 5000 edges per bin block (exact)
#define CAP 1536                  // slots per bucket region (mean 1024, 16 sigma)
#define MTILES (N_NODES / 16)     // 6250 row-tiles for MFMA gemm (exact)
#define GEMM_BLKS ((MTILES + 15) / 16)   // 391 gemm blocks (16 waves x 1 tile)

// bin LDS layout (union with gemm's wt)
#define SBUF_B (EPA * 8)                  // 40000
#define HH_OFF SBUF_B                     // int hh[NB]
#define DD_OFF (SBUF_B + 6256)            // int dd[NB]
#define SK_OFF (SBUF_B + 6256 + 6256)     // ushort sk[EPA]
#define SMEM_B (SK_OFF + EPA * 2 + 16)    // ~62.5 KB

typedef __attribute__((ext_vector_type(8))) short bf16x8;
typedef __attribute__((ext_vector_type(4))) float f32x4;

__device__ __forceinline__ float bf2f(unsigned short u) {
    return __uint_as_float(((uint32_t)u) << 16);
}
__device__ __forceinline__ unsigned short f2bf(float x) {
    const uint32_t b = __float_as_uint(x);
    return (unsigned short)((b + 0x7fffu + ((b >> 16) & 1u)) >> 16);   // RNE
}
__device__ __forceinline__ long long pack_rec(int r, int c, uint32_t v) {
    return (long long)(((uint64_t)v << 32) |
           (uint64_t)((uint32_t)c | ((uint32_t)(r & 63) << 17)));
}

// ---------------------------------------------------------------------------
// K0: init bucket cursors to region bases; zero overflow counter.
// ---------------------------------------------------------------------------
__global__ __launch_bounds__(256) void gcn_init(int* __restrict__ cur,
                                                int* __restrict__ ovf_cnt) {
    const int i = blockIdx.x * 256 + threadIdx.x;
    if (i < NB) cur[i] = i * CAP;
    if (i == NB) *ovf_cnt = 0;
}

// ---------------------------------------------------------------------------
// K1 (fused, 1024 thr): blocks [0,GEMM_BLKS) = MFMA GEMM (16 tiles/block);
// blocks [GEMM_BLKS,+BBLK) = bin v2: LDS hist -> chunked block scan ->
// global reservation -> LDS bucket-sorted placement -> BURST write (ordered,
// atomic-free stores; segment-consecutive addresses).
// ---------------------------------------------------------------------------
__global__ __launch_bounds__(1024) void gcn_gemm_bin(const float* __restrict__ x,
                                                     const float* __restrict__ w,
                                                     unsigned short* __restrict__ support,
                                                     const int* __restrict__ row,
                                                     const int* __restrict__ col,
                                                     const float* __restrict__ val,
                                                     int* __restrict__ cur,
                                                     int* __restrict__ ovf_cnt,
                                                     long long* __restrict__ rec,
                                                     long long* __restrict__ ovf_pk,
                                                     int* __restrict__ ovf_bk) {
    __shared__ __align__(16) char smem[SMEM_B];
    const int tid = threadIdx.x;

    if (blockIdx.x < GEMM_BLKS) {
        // ---------------- GEMM: support = bf16(x @ W) ----------------
        unsigned short (*wt)[IN_F + 8] =
            reinterpret_cast<unsigned short (*)[IN_F + 8]>(smem);
        #pragma unroll
        for (int i = tid; i < IN_F * OUT_F; i += 1024) {
            const int k = i >> 5, f = i & 31;
            wt[f][k] = f2bf(w[i]);
        }
        __syncthreads();

        const int wv = tid >> 6;                 // wave 0..15
        const int lane = tid & 63;
        const int rowT = blockIdx.x * 16 + wv;   // 16-row tile index
        if (rowT >= MTILES) return;
        const int row0 = rowT * 16;

        const int mrow = lane & 15;              // A row / C col index
        const int kg = lane >> 4;                // k-group 0..3
        const int kb = kg * 8;

        bf16x8 bfrag[4][2];
        #pragma unroll
        for (int ks = 0; ks < 4; ++ks) {
            #pragma unroll
            for (int nt = 0; nt < 2; ++nt) {
                bfrag[ks][nt] = *reinterpret_cast<const bf16x8*>(
                    &wt[mrow + nt * 16][ks * 32 + kb]);
            }
        }

        f32x4 acc0 = {0.f, 0.f, 0.f, 0.f};
        f32x4 acc1 = {0.f, 0.f, 0.f, 0.f};
        const float* xr = &x[(size_t)(row0 + mrow) * IN_F];
        #pragma unroll
        for (int ks = 0; ks < 4; ++ks) {
            const float4 a0 = *reinterpret_cast<const float4*>(&xr[ks * 32 + kb]);
            const float4 a1 = *reinterpret_cast<const float4*>(&xr[ks * 32 + kb + 4]);
            bf16x8 af;
            af[0] = (short)f2bf(a0.x); af[1] = (short)f2bf(a0.y);
            af[2] = (short)f2bf(a0.z); af[3] = (short)f2bf(a0.w);
            af[4] = (short)f2bf(a1.x); af[5] = (short)f2bf(a1.y);
            af[6] = (short)f2bf(a1.z); af[7] = (short)f2bf(a1.w);
            acc0 = __builtin_amdgcn_mfma_f32_16x16x32_bf16(af, bfrag[ks][0], acc0, 0, 0, 0);
            acc1 = __builtin_amdgcn_mfma_f32_16x16x32_bf16(af, bfrag[ks][1], acc1, 0, 0, 0);
        }
        #pragma unroll
        for (int r = 0; r < 4; ++r) {
            const int orow = row0 + kg * 4 + r;
            support[(size_t)orow * OUT_F + mrow]      = f2bf(acc0[r]);
            support[(size_t)orow * OUT_F + mrow + 16] = f2bf(acc1[r]);
        }
    } else {
        // -------- BIN v2: hist -> scan -> reserve -> LDS sort -> burst --------
        long long* sbuf = reinterpret_cast<long long*>(smem);
        int* hh = reinterpret_cast<int*>(smem + HH_OFF);
        int* dd = reinterpret_cast<int*>(smem + DD_OFF);     // also scan buffer
        unsigned short* sk = reinterpret_cast<unsigned short*>(smem + SK_OFF);

        const int b = blockIdx.x - GEMM_BLKS;
        const int e0 = b * EPA;
        const int i4 = tid + 4096;
        const bool has4 = (i4 < EPA);            // EPA=5000: true for tid<904

        for (int i = tid; i < NB; i += 1024) hh[i] = 0;
        __syncthreads();

        // hist (rows held in registers; col/val re-read later, L2-hot)
        const int r0 = row[e0 + tid];
        const int r1 = row[e0 + tid + 1024];
        const int r2 = row[e0 + tid + 2048];
        const int r3 = row[e0 + tid + 3072];
        const int r4 = has4 ? row[e0 + i4] : 0;
        atomicAdd(&hh[r0 >> 6], 1);
        atomicAdd(&hh[r1 >> 6], 1);
        atomicAdd(&hh[r2 >> 6], 1);
        atomicAdd(&hh[r3 >> 6], 1);
        if (has4) atomicAdd(&hh[r4 >> 6], 1);
        __syncthreads();

        // chunked exclusive scan of hh[0..NB): thread t owns [2t, 2t+1]
        int cntA = 0, cntB = 0;
        if (tid < 782) {
            cntA = hh[2 * tid];
            cntB = (2 * tid + 1 < NB) ? hh[2 * tid + 1] : 0;
        }
        const int csum = cntA + cntB;
        dd[tid] = csum;                 // dd doubles as 1024-int scan buffer
        __syncthreads();
        for (int off = 1; off < 1024; off <<= 1) {
            const int v2 = (tid >= off) ? dd[tid - off] : 0;
            __syncthreads();
            dd[tid] += v2;
            __syncthreads();
        }
        const int excl = dd[tid] - csum;
        __syncthreads();                // all scan reads done before overwrite
        if (tid < 782) {
            const int k0 = 2 * tid, k1 = 2 * tid + 1;
            const int lo0 = excl, lo1 = excl + cntA;
            int D0 = 0, D1 = 0;
            if (cntA > 0) D0 = atomicAdd(&cur[k0], cntA) - lo0;
            hh[k0] = lo0; dd[k0] = D0;
            if (k1 < NB) {
                if (cntB > 0) D1 = atomicAdd(&cur[k1], cntB) - lo1;
                hh[k1] = lo1; dd[k1] = D1;
            }
        }
        __syncthreads();

        // placement into bucket-sorted LDS order (cursor = hh)
        {
            const int c0 = col[e0 + tid];
            const int c1 = col[e0 + tid + 1024];
            const int c2 = col[e0 + tid + 2048];
            const int c3 = col[e0 + tid + 3072];
            const uint32_t v0 = __float_as_uint(val[e0 + tid]);
            const uint32_t v1 = __float_as_uint(val[e0 + tid + 1024]);
            const uint32_t v2 = __float_as_uint(val[e0 + tid + 2048]);
            const uint32_t v3 = __float_as_uint(val[e0 + tid + 3072]);
            const int k0 = r0 >> 6, k1 = r1 >> 6, k2 = r2 >> 6, k3 = r3 >> 6;
            const int s0 = atomicAdd(&hh[k0], 1);
            const int s1 = atomicAdd(&hh[k1], 1);
            const int s2 = atomicAdd(&hh[k2], 1);
            const int s3 = atomicAdd(&hh[k3], 1);
            sbuf[s0] = pack_rec(r0, c0, v0); sk[s0] = (unsigned short)k0;
            sbuf[s1] = pack_rec(r1, c1, v1); sk[s1] = (unsigned short)k1;
            sbuf[s2] = pack_rec(r2, c2, v2); sk[s2] = (unsigned short)k2;
            sbuf[s3] = pack_rec(r3, c3, v3); sk[s3] = (unsigned short)k3;
            if (has4) {
                const int c4 = col[e0 + i4];
                const uint32_t v4 = __float_as_uint(val[e0 + i4]);
                const int k4 = r4 >> 6;
                const int s4 = atomicAdd(&hh[k4], 1);
                sbuf[s4] = pack_rec(r4, c4, v4); sk[s4] = (unsigned short)k4;
            }
        }
        __syncthreads();

        // burst write: consecutive i -> consecutive addresses within segments
        for (int i = tid; i < EPA; i += 1024) {
            const int k = (int)sk[i];
            const long long pk = sbuf[i];
            const int ga = dd[k] + i;
            if (ga < (k + 1) * CAP) {
                rec[ga] = pk;
            } else {                               // statistically never
                const int oi = atomicAdd(ovf_cnt, 1);
                ovf_pk[oi] = pk;
                ovf_bk[oi] = k;
            }
        }
    }
}

// ---------------------------------------------------------------------------
// K2: 1024 threads (32 row-groups x 2 passes), one block per bucket.
// LDS counting-sort to exact row order, then register accumulation with an
// 8-deep unrolled gather pipeline. Bucket span read straight from cur[].
// ---------------------------------------------------------------------------
__global__ __launch_bounds__(1024) void gcn_rows(const int* __restrict__ cur,
                                                 const int* __restrict__ ovf_cnt,
                                                 const long long* __restrict__ rec,
                                                 const long long* __restrict__ ovf_pk,
                                                 const int* __restrict__ ovf_bk,
                                                 const unsigned short* __restrict__ sup,
                                                 const float* __restrict__ bias,
                                                 float* __restrict__ out) {
    __shared__ long long rbuf[CAP];    // 12 KB
    __shared__ long long srt[CAP];     // 12 KB
    __shared__ int cnt[RB];            // reused as cursor after scan
    __shared__ int rs[RB + 1];         // row segment starts
    __shared__ float bs[OUT_F];
    const int tid = threadIdx.x, k = blockIdx.x;

    const int start = k * CAP;
    const int total = cur[k] - start;          // bucket count (incl. spilled)
    const int n = min(total, CAP);             // in-region records
    const int novf = *ovf_cnt;                 // normally 0

    if (tid < OUT_F) bs[tid] = bias[tid];
    if (tid < RB) cnt[tid] = 0;
    for (int i = tid; i < n; i += 1024) rbuf[i] = rec[start + i];   // coalesced stage
    __syncthreads();

    for (int i = tid; i < n; i += 1024)
        atomicAdd(&cnt[(int)(((uint64_t)rbuf[i] >> 17) & 63)], 1);
    __syncthreads();

    if (tid < 64) {      // exclusive scan of 64 counters in wave 0
        const int v = cnt[tid];
        int sc = v;
        #pragma unroll
        for (int d = 1; d < 64; d <<= 1) {
            const int t2 = __shfl_up(sc, d, 64);
            if (tid >= d) sc += t2;
        }
        rs[tid] = sc - v;
        cnt[tid] = sc - v;
        if (tid == 63) rs[64] = sc;
    }
    __syncthreads();

    for (int i = tid; i < n; i += 1024) {       // reorder into exact row order
        const long long pk = rbuf[i];
        const int rl = (int)(((uint64_t)pk >> 17) & 63);
        const int slot = atomicAdd(&cnt[rl], 1);
        srt[slot] = pk;
    }
    __syncthreads();

    // register accumulation: 32 groups x 2 passes = 64 rows
    const int g = tid >> 5;           // row-group 0..31
    const int f = tid & 31;           // feature
    const int rowBase = k * RB;

    for (int rp = 0; rp < 2; ++rp) {
        const int r = rp * 32 + g;
        const int gr = rowBase + r;
        const int s0 = rs[r];
        const int s1 = rs[r + 1];
        float a0 = bs[f], a1 = 0.f, a2 = 0.f, a3 = 0.f;
        int i = s0;
        for (; i + 8 <= s1; i += 8) {
            const uint64_t p0 = (uint64_t)srt[i];
            const uint64_t p1 = (uint64_t)srt[i + 1];
            const uint64_t p2 = (uint64_t)srt[i + 2];
            const uint64_t p3 = (uint64_t)srt[i + 3];
            const uint64_t p4 = (uint64_t)srt[i + 4];
            const uint64_t p5 = (uint64_t)srt[i + 5];
            const uint64_t p6 = (uint64_t)srt[i + 6];
            const uint64_t p7 = (uint64_t)srt[i + 7];
            const unsigned short q0 = sup[(size_t)(p0 & 0x1ffff) * OUT_F + f];
            const unsigned short q1 = sup[(size_t)(p1 & 0x1ffff) * OUT_F + f];
            const unsigned short q2 = sup[(size_t)(p2 & 0x1ffff) * OUT_F + f];
            const unsigned short q3 = sup[(size_t)(p3 & 0x1ffff) * OUT_F + f];
            const unsigned short q4 = sup[(size_t)(p4 & 0x1ffff) * OUT_F + f];
            const unsigned short q5 = sup[(size_t)(p5 & 0x1ffff) * OUT_F + f];
            const unsigned short q6 = sup[(size_t)(p6 & 0x1ffff) * OUT_F + f];
            const unsigned short q7 = sup[(size_t)(p7 & 0x1ffff) * OUT_F + f];
            a0 += __uint_as_float((uint32_t)(p0 >> 32)) * bf2f(q0);
            a1 += __uint_as_float((uint32_t)(p1 >> 32)) * bf2f(q1);
            a2 += __uint_as_float((uint32_t)(p2 >> 32)) * bf2f(q2);
            a3 += __uint_as_float((uint32_t)(p3 >> 32)) * bf2f(q3);
            a0 += __uint_as_float((uint32_t)(p4 >> 32)) * bf2f(q4);
            a1 += __uint_as_float((uint32_t)(p5 >> 32)) * bf2f(q5);
            a2 += __uint_as_float((uint32_t)(p6 >> 32)) * bf2f(q6);
            a3 += __uint_as_float((uint32_t)(p7 >> 32)) * bf2f(q7);
        }
        for (; i + 4 <= s1; i += 4) {
            const uint64_t p0 = (uint64_t)srt[i];
            const uint64_t p1 = (uint64_t)srt[i + 1];
            const uint64_t p2 = (uint64_t)srt[i + 2];
            const uint64_t p3 = (uint64_t)srt[i + 3];
            const unsigned short q0 = sup[(size_t)(p0 & 0x1ffff) * OUT_F + f];
            const unsigned short q1 = sup[(size_t)(p1 & 0x1ffff) * OUT_F + f];
            const unsigned short q2 = sup[(size_t)(p2 & 0x1ffff) * OUT_F + f];
            const unsigned short q3 = sup[(size_t)(p3 & 0x1ffff) * OUT_F + f];
            a0 += __uint_as_float((uint32_t)(p0 >> 32)) * bf2f(q0);
            a1 += __uint_as_float((uint32_t)(p1 >> 32)) * bf2f(q1);
            a2 += __uint_as_float((uint32_t)(p2 >> 32)) * bf2f(q2);
            a3 += __uint_as_float((uint32_t)(p3 >> 32)) * bf2f(q3);
        }
        for (; i < s1; ++i) {
            const uint64_t pk = (uint64_t)srt[i];
            const unsigned short q = sup[(size_t)(pk & 0x1ffff) * OUT_F + f];
            a0 += __uint_as_float((uint32_t)(pk >> 32)) * bf2f(q);
        }
        // overflow list (normally empty; correctness guard)
        for (int j = 0; j < novf; ++j) {
            if (ovf_bk[j] == k) {
                const uint64_t pk = (uint64_t)ovf_pk[j];
                if ((int)((pk >> 17) & 63) == r) {
                    const unsigned short q = sup[(size_t)(pk & 0x1ffff) * OUT_F + f];
                    a0 += __uint_as_float((uint32_t)(pk >> 32)) * bf2f(q);
                }
            }
        }
        if (gr < N_NODES)
            out[(size_t)gr * OUT_F + f] = (a0 + a1) + (a2 + a3);
    }
}

// ---------------------------------------------------------------------------
// Fallback path (ws too small): gemm-only + atomic scatter
// ---------------------------------------------------------------------------
__global__ __launch_bounds__(256) void gcn_bias_init(const float* __restrict__ bias,
                                                     float* __restrict__ out) {
    const int i = blockIdx.x * 256 + threadIdx.x;
    if (i < N_NODES * OUT_F) out[i] = bias[i & 31];
}

__global__ __launch_bounds__(512) void gcn_gemm_only(const float* __restrict__ x,
                                                     const float* __restrict__ w,
                                                     unsigned short* __restrict__ support) {
    __shared__ unsigned short wt[OUT_F][IN_F + 8];
    const int tid = threadIdx.x;
    #pragma unroll
    for (int i = tid; i < IN_F * OUT_F; i += 512) {
        const int k = i >> 5, f = i & 31;
        wt[f][k] = f2bf(w[i]);
    }
    __syncthreads();
    const int wv = tid >> 6;
    const int lane = tid & 63;
    const int rowT = blockIdx.x * 8 + wv;
    if (rowT >= MTILES) return;
    const int row0 = rowT * 16;
    const int mrow = lane & 15;
    const int kg = lane >> 4;
    const int kb = kg * 8;
    bf16x8 bfrag[4][2];
    #pragma unroll
    for (int ks = 0; ks < 4; ++ks)
        #pragma unroll
        for (int nt = 0; nt < 2; ++nt)
            bfrag[ks][nt] = *reinterpret_cast<const bf16x8*>(
                &wt[mrow + nt * 16][ks * 32 + kb]);
    f32x4 acc0 = {0.f, 0.f, 0.f, 0.f};
    f32x4 acc1 = {0.f, 0.f, 0.f, 0.f};
    const float* xr = &x[(size_t)(row0 + mrow) * IN_F];
    #pragma unroll
    for (int ks = 0; ks < 4; ++ks) {
        const float4 a0 = *reinterpret_cast<const float4*>(&xr[ks * 32 + kb]);
        const float4 a1 = *reinterpret_cast<const float4*>(&xr[ks * 32 + kb + 4]);
        bf16x8 af;
        af[0] = (short)f2bf(a0.x); af[1] = (short)f2bf(a0.y);
        af[2] = (short)f2bf(a0.z); af[3] = (short)f2bf(a0.w);
        af[4] = (short)f2bf(a1.x); af[5] = (short)f2bf(a1.y);
        af[6] = (short)f2bf(a1.z); af[7] = (short)f2bf(a1.w);
        acc0 = __builtin_amdgcn_mfma_f32_16x16x32_bf16(af, bfrag[ks][0], acc0, 0, 0, 0);
        acc1 = __builtin_amdgcn_mfma_f32_16x16x32_bf16(af, bfrag[ks][1], acc1, 0, 0, 0);
    }
    #pragma unroll
    for (int r = 0; r < 4; ++r) {
        const int orow = row0 + kg * 4 + r;
        support[(size_t)orow * OUT_F + mrow]      = f2bf(acc0[r]);
        support[(size_t)orow * OUT_F + mrow + 16] = f2bf(acc1[r]);
    }
}

__global__ __launch_bounds__(256) void gcn_scatter(const int* __restrict__ row,
                                                   const int* __restrict__ col,
                                                   const float* __restrict__ val,
                                                   const unsigned short* __restrict__ sup,
                                                   float* __restrict__ out) {
    const int f = threadIdx.x & 31;
    const int grp = threadIdx.x >> 5;
    long long e = (long long)blockIdx.x * 8 + grp;
    const long long stride = (long long)gridDim.x * 8;
    for (; e < N_EDGES; e += stride) {
        const int r = row[e];
        const int c = col[e];
        const float v = val[e];
        const float s = bf2f(sup[(size_t)c * OUT_F + f]);
        atomicAdd(&out[(size_t)r * OUT_F + f], v * s);
    }
}

extern "C" void kernel_launch(void* const* d_in, const int* in_sizes, int n_in,
                              void* d_out, int out_size, void* d_ws, size_t ws_size,
                              hipStream_t stream) {
    const float* x       = (const float*)d_in[0];
    const int*   adj_row = (const int*)d_in[1];
    const int*   adj_col = (const int*)d_in[2];
    const float* adj_val = (const float*)d_in[3];
    const float* weight  = (const float*)d_in[4];
    const float* bias    = (const float*)d_in[5];
    float* out = (float*)d_out;

    char* ws = (char*)d_ws;
    const size_t SUPPORT_B = (((size_t)N_NODES * OUT_F * 2) + 255) & ~(size_t)255;  // 6.4 MB
    const size_t REC_B     = (((size_t)NB * CAP * 8) + 255) & ~(size_t)255;         // 19.2 MB
    const size_t CUR_B     = (((size_t)NB * 4) + 255) & ~(size_t)255;
    const size_t OCN_B     = 256;
    const size_t OPK_B     = (size_t)N_EDGES * 8;                                   // 12.8 MB
    const size_t OBK_B     = (size_t)N_EDGES * 4;                                   // 6.4 MB
    const size_t NEED = SUPPORT_B + REC_B + CUR_B + OCN_B + OPK_B + OBK_B;

    unsigned short* support = (unsigned short*)(ws);
    long long* rec  = (long long*)(ws + SUPPORT_B);
    int* cur        = (int*)(ws + SUPPORT_B + REC_B);
    int* ovf_cnt    = (int*)(ws + SUPPORT_B + REC_B + CUR_B);
    long long* ovf_pk = (long long*)(ws + SUPPORT_B + REC_B + CUR_B + OCN_B);
    int* ovf_bk     = (int*)(ws + SUPPORT_B + REC_B + CUR_B + OCN_B + OPK_B);

    if (ws_size >= NEED) {
        // K0: cursor init
        gcn_init<<<(NB + 256) / 256, 256, 0, stream>>>(cur, ovf_cnt);
        // K1: fused MFMA gemm || LDS-sorted bin (hist -> scan -> reserve -> burst)
        gcn_gemm_bin<<<GEMM_BLKS + BBLK, 1024, 0, stream>>>(x, weight, support,
                                                            adj_row, adj_col, adj_val,
                                                            cur, ovf_cnt, rec,
                                                            ovf_pk, ovf_bk);
        // K2: per-bucket counting-sort + 8-deep pipelined register gather
        gcn_rows<<<NB, 1024, 0, stream>>>(cur, ovf_cnt, rec, ovf_pk, ovf_bk,
                                          support, bias, out);
    } else {
        gcn_gemm_only<<<(MTILES + 7) / 8, 512, 0, stream>>>(x, weight, support);
        gcn_bias_init<<<(N_NODES * OUT_F + 255) / 256, 256, 0, stream>>>(bias, out);
        gcn_scatter<<<8192, 256, 0, stream>>>(adj_row, adj_col, adj_val, support, out);
    }
}